// Round 5
// baseline (120.665 us; speedup 1.0000x reference)
//
#include <hip/hip_runtime.h>
#include <hip/hip_cooperative_groups.h>
#include <math.h>

namespace cg = cooperative_groups;

#define NP 1024          // proposals
#define NC 81            // classes incl background
#define CF 80            // foreground classes
#define DET 100          // detections per image
#define SCORE_THRESH 0.05f
#define NMS_THRESH 0.5f
#define BBOX_CLIP 4.135166556742356f   // log(1000/16)
#define IMG_W 1333
#define IMG_H 800

#define NCAND (CF * DET)   // 8000 fixed per-class slots
#define NT 512             // block size (8 waves)
#define NW (NT / 64)       // waves per block

// histogram-select: bucket = clamp((key>>31) - HOFF, 0, HB-1).
// key>>31 == score_bits>>15; score in (0.05, 1] -> raw in [31385, 32512].
// Monotone non-decreasing in key => selection EXACT (same-bucket ties are
// resolved on the full unique 64-bit key; top clamp merges scores >~0.62,
// which only grows the qualifier set, never changes ranks).
#define HB   1024
#define HOFF 31385

__device__ __forceinline__ int bucketOf(unsigned long long k) {
    int b = (int)(unsigned)(k >> 31) - HOFF;
    b = b < 0 ? 0 : b;
    b = b > HB - 1 ? HB - 1 : b;
    return b;
}

// ---------------------------------------------------------------------------
// Single cooperative kernel, 80 blocks x 512 threads (1 block/CU at ~101KB
// LDS; 80 << 256 CUs -> co-residency guaranteed, grid.sync() safe).
//
// Phase A: distributed softmax — 640 waves, each runs the PROVEN bit-exact
//          per-proposal wave computation (proposals gw and gw+640).
// grid.sync()
// Phase B: per-class NMS (R4 verbatim: fast ballot path / bitonic slow path).
// grid.sync()
// Phase T: block 0 only — histogram-select topk (R4 verbatim) + zero-fill of
//          output rows [K, DET) (ranks are dense -> rows < min(K,DET) are
//          fully written by winners). No done counter, no out pre-zeroing.
// ---------------------------------------------------------------------------
__global__ __launch_bounds__(NT) void
fused_kernel(const float* __restrict__ logits,
             const float* __restrict__ rel,
             const float* __restrict__ props,
             unsigned long long* __restrict__ gkeys,
             float4* __restrict__ gboxes,
             int* __restrict__ gcnt,
             float* __restrict__ scores_fg,
             float* __restrict__ out) {
    cg::grid_group grid = cg::this_grid();
    const int cls = blockIdx.x;   // fg class (reference class = cls+1)
    const int tid = threadIdx.x;  // 0..511

    // phase-B arrays union with phase-T keysh (phase-B data dead by then)
    __shared__ __align__(16) unsigned char smem[NCAND * 8];   // 64000 B
    __shared__ int hist[HB];          // 4 KB (phase T: counts, then suffix S)
    __shared__ int qidx[NCAND];       // 32 KB (phase T qualifier list)
    __shared__ int wtot[NW];          // per-wave totals for suffix scan
    __shared__ int cntSh;
    __shared__ int keptRank[DET];
    __shared__ int keptCnt;
    __shared__ int cshare[CF];
    __shared__ int cbase[CF + 1];
    __shared__ int qnSh;

    unsigned long long* key = (unsigned long long*)smem;             // 8 KB
    float4* vbox = (float4*)(smem + 8192);                           // 16 KB
    unsigned char* supp = (unsigned char*)(smem + 8192 + 16384);     // 1 KB

    // ---------------- Phase A: distributed softmax (bit-exact waves) --------
    {
        const int gw   = blockIdx.x * NW + (tid >> 6);   // global wave 0..639
        const int lane = tid & 63;
        for (int i = gw; i < NP; i += CF * NW) {         // i = gw, gw+640
            const float x0 = logits[i * NC + lane];
            const float x1 = (lane < NC - 64) ? logits[i * NC + 64 + lane]
                                              : -INFINITY;

            float m = fmaxf(x0, x1);
            for (int off = 32; off > 0; off >>= 1) m = fmaxf(m, __shfl_xor(m, off));

            const float e0 = expf(x0 - m);
            const float e1 = (lane < NC - 64) ? expf(x1 - m) : 0.0f;
            float sum = e0 + e1;
            for (int off = 32; off > 0; off >>= 1) sum += __shfl_xor(sum, off);

            if (lane >= 1) scores_fg[(lane - 1) * NP + i] = e0 / sum;
            if (lane < NC - 64) scores_fg[(64 + lane - 1) * NP + i] = e1 / sum;
        }
    }

    grid.sync();   // scores visible to all blocks (device-scope fence inside)

    // ---------------- Phase B: per-class NMS (R4 verbatim) ------------------
    if (tid == 0) cntSh = 0;
    __syncthreads();

    // threshold compaction: 1024 scores, 1 float4 per thread (tid<256)
    if (tid < NP / 4) {
        const float4* srow = (const float4*)(scores_fg + cls * NP);
        const float4 v = srow[tid];
        const int id0 = tid * 4;
        if (v.x > SCORE_THRESH) { int p = atomicAdd(&cntSh, 1); key[p] = ((unsigned long long)__float_as_uint(v.x) << 16) | (unsigned long long)(1023 - (id0 + 0)); }
        if (v.y > SCORE_THRESH) { int p = atomicAdd(&cntSh, 1); key[p] = ((unsigned long long)__float_as_uint(v.y) << 16) | (unsigned long long)(1023 - (id0 + 1)); }
        if (v.z > SCORE_THRESH) { int p = atomicAdd(&cntSh, 1); key[p] = ((unsigned long long)__float_as_uint(v.z) << 16) | (unsigned long long)(1023 - (id0 + 2)); }
        if (v.w > SCORE_THRESH) { int p = atomicAdd(&cntSh, 1); key[p] = ((unsigned long long)__float_as_uint(v.w) << 16) | (unsigned long long)(1023 - (id0 + 3)); }
    }
    __syncthreads();
    const int cnt = cntSh;

    if (cnt == 0) {
        if (tid == 0) gcnt[cls] = 0;
    } else if (cnt <= 64) {
        // ================== FAST PATH: cnt<=64 (wave 0 active) ==============
        unsigned long long my = 0ull;
        int rk = 0;
        if (tid < cnt) {
            my = key[tid];
            for (int i = 0; i < cnt; ++i) rk += (key[i] > my) ? 1 : 0;
        }
        __syncthreads();
        if (tid < cnt) key[rk] = my;
        __syncthreads();

        if (tid < cnt) {
            const int id = 1023 - (int)(key[tid] & 0xFFFFull);
            const float4 p = ((const float4*)props)[id];
            const float w  = p.z - p.x + 1.0f;
            const float h  = p.w - p.y + 1.0f;
            const float cx = p.x + 0.5f * w;
            const float cy = p.y + 0.5f * h;

            const float4 r = ((const float4*)rel)[id * NC + (cls + 1)];
            const float dx = r.x / 10.0f;
            const float dy = r.y / 10.0f;
            const float dw = fminf(r.z / 5.0f, BBOX_CLIP);
            const float dh = fminf(r.w / 5.0f, BBOX_CLIP);

            const float pcx = dx * w + cx;
            const float pcy = dy * h + cy;
            const float pw  = expf(dw) * w;
            const float ph  = expf(dh) * h;

            float bx1 = pcx - 0.5f * pw;
            float by1 = pcy - 0.5f * ph;
            float bx2 = pcx + 0.5f * pw - 1.0f;
            float by2 = pcy + 0.5f * ph - 1.0f;

            bx1 = fminf(fmaxf(bx1, 0.0f), (float)(IMG_W - 1));
            bx2 = fminf(fmaxf(bx2, 0.0f), (float)(IMG_W - 1));
            by1 = fminf(fmaxf(by1, 0.0f), (float)(IMG_H - 1));
            by2 = fminf(fmaxf(by2, 0.0f), (float)(IMG_H - 1));

            vbox[tid] = make_float4(bx1, by1, bx2, by2);
        }
        __syncthreads();

        unsigned long long mymask = 0ull;
        if (tid < cnt) {
            const float4 bj = vbox[tid];
            const float areaj = (bj.z - bj.x + 1.0f) * (bj.w - bj.y + 1.0f);
            for (int i = 0; i < tid; ++i) {
                const float4 bi = vbox[i];            // LDS broadcast
                const float areai = (bi.z - bi.x + 1.0f) * (bi.w - bi.y + 1.0f);
                const float ltx = fmaxf(bi.x, bj.x);
                const float lty = fmaxf(bi.y, bj.y);
                const float rbx = fminf(bi.z, bj.z);
                const float rby = fminf(bi.w, bj.w);
                const float wq = fmaxf(rbx - ltx + 1.0f, 0.0f);
                const float hq = fmaxf(rby - lty + 1.0f, 0.0f);
                const float inter = wq * hq;
                const float iou = inter / (areai + areaj - inter);
                if (iou > NMS_THRESH) mymask |= (1ull << i);
            }
        }
        // resolve in every wave; only wave-0 results are used (tid<cnt<=64)
        unsigned long long suppbits = 0ull;
        for (int i = 0; i < cnt; ++i) {
            if (!((suppbits >> i) & 1ull)) {
                const unsigned long long vote = __ballot((mymask >> i) & 1ull);
                suppbits |= vote;
            }
        }
        unsigned long long kb = ~suppbits;
        if (cnt < 64) kb &= ((1ull << cnt) - 1ull);
        const int c2 = __popcll(kb);

        if (tid == 0) gcnt[cls] = c2;
        if (tid < cnt && !((suppbits >> tid) & 1ull)) {
            const int kr = __popcll(kb & ((1ull << tid) - 1ull));
            const int slot = cls * DET + kr;
            const unsigned int bits = (unsigned int)(key[tid] >> 16);
            gkeys[slot] = ((unsigned long long)bits << 16) |
                          (unsigned long long)(65535 - slot);
            gboxes[slot] = vbox[tid];
        }
    } else {
        // ===================== SLOW PATH: cnt>64 ============================
        int msz = 1;
        while (msz < cnt) msz <<= 1;
        for (int t = cnt + tid; t < msz; t += NT) key[t] = 0ull;
        __syncthreads();

        for (int k = 2; k <= msz; k <<= 1) {
            for (int jj = k >> 1; jj > 0; jj >>= 1) {
                for (int t = tid; t < msz; t += NT) {
                    const int ixj = t ^ jj;
                    if (ixj > t) {
                        const unsigned long long a = key[t], b = key[ixj];
                        const bool tAfter = (a < b);
                        const bool dirAsc = ((t & k) == 0);
                        if (dirAsc ? tAfter : !tAfter) { key[t] = b; key[ixj] = a; }
                    }
                }
                __syncthreads();
            }
        }

        for (int t = tid; t < cnt; t += NT) {
            const int id = 1023 - (int)(key[t] & 0xFFFFull);
            const float4 p = ((const float4*)props)[id];
            const float w  = p.z - p.x + 1.0f;
            const float h  = p.w - p.y + 1.0f;
            const float cx = p.x + 0.5f * w;
            const float cy = p.y + 0.5f * h;

            const float4 r = ((const float4*)rel)[id * NC + (cls + 1)];
            const float dx = r.x / 10.0f;
            const float dy = r.y / 10.0f;
            const float dw = fminf(r.z / 5.0f, BBOX_CLIP);
            const float dh = fminf(r.w / 5.0f, BBOX_CLIP);

            const float pcx = dx * w + cx;
            const float pcy = dy * h + cy;
            const float pw  = expf(dw) * w;
            const float ph  = expf(dh) * h;

            float bx1 = pcx - 0.5f * pw;
            float by1 = pcy - 0.5f * ph;
            float bx2 = pcx + 0.5f * pw - 1.0f;
            float by2 = pcy + 0.5f * ph - 1.0f;

            bx1 = fminf(fmaxf(bx1, 0.0f), (float)(IMG_W - 1));
            bx2 = fminf(fmaxf(bx2, 0.0f), (float)(IMG_W - 1));
            by1 = fminf(fmaxf(by1, 0.0f), (float)(IMG_H - 1));
            by2 = fminf(fmaxf(by2, 0.0f), (float)(IMG_H - 1));

            vbox[t] = make_float4(bx1, by1, bx2, by2);
            supp[t] = 0;
        }
        __syncthreads();

        for (int i = 0; i < cnt; ++i) {
            if (!supp[i]) {
                const float4 bi = vbox[i];
                const float areai = (bi.z - bi.x + 1.0f) * (bi.w - bi.y + 1.0f);
                for (int t = i + 1 + tid; t < cnt; t += NT) {
                    const float4 bj = vbox[t];
                    const float areaj = (bj.z - bj.x + 1.0f) * (bj.w - bj.y + 1.0f);
                    const float ltx = fmaxf(bi.x, bj.x);
                    const float lty = fmaxf(bi.y, bj.y);
                    const float rbx = fminf(bi.z, bj.z);
                    const float rby = fminf(bi.w, bj.w);
                    const float wq = fmaxf(rbx - ltx + 1.0f, 0.0f);
                    const float hq = fmaxf(rby - lty + 1.0f, 0.0f);
                    const float inter = wq * hq;
                    const float iou = inter / (areai + areaj - inter);
                    if (iou > NMS_THRESH) supp[t] = 1;
                }
            }
            __syncthreads();
        }

        if (tid == 0) {
            int c2 = 0;
            for (int r = 0; r < cnt && c2 < DET; ++r)
                if (!supp[r]) keptRank[c2++] = r;
            keptCnt = c2;
            gcnt[cls] = c2;
        }
        __syncthreads();

        const int kc = keptCnt;
        for (int t = tid; t < kc; t += NT) {
            const int r = keptRank[t];
            const int slot = cls * DET + t;
            const unsigned int bits = (unsigned int)(key[r] >> 16);
            gkeys[slot] = ((unsigned long long)bits << 16) |
                          (unsigned long long)(65535 - slot);
            gboxes[slot] = vbox[r];
        }
    }

    grid.sync();   // all classes' gkeys/gboxes/gcnt visible

    if (cls != 0) return;   // 79 blocks retire; block 0 runs phase T

    // ---------------- Phase T: single-block histogram-select topk -----------
    if (tid < CF) cshare[tid] = gcnt[tid];
    __syncthreads();
    if (tid <= CF) {
        int acc = 0;
        for (int i = 0; i < tid; ++i) acc += cshare[i];   // independent loads
        cbase[tid] = acc;
    }
    for (int t = tid; t < HB; t += NT) hist[t] = 0;
    __syncthreads();
    const int K = cbase[CF];

    // zero-fill output rows [K, DET) — ranks are dense, so rows < min(K,DET)
    // are each written exactly once by their winner below.
    for (int r = K + tid; r < DET; r += NT) {
        out[r * 4 + 0] = 0.0f; out[r * 4 + 1] = 0.0f;
        out[r * 4 + 2] = 0.0f; out[r * 4 + 3] = 0.0f;
        out[4 * DET + r] = 0.0f;
        out[5 * DET + r] = 0.0f;
    }

    // flat parallel gather of the compacted key array (coalesced, ~16 iters)
    unsigned long long* keysh = (unsigned long long*)smem;   // reuses phase-B
    for (int g = tid; g < NCAND; g += NT) {
        const int c = g / DET;          // const-div -> magic mul
        const int j = g - c * DET;
        if (j < cshare[c]) keysh[cbase[c] + j] = gkeys[g];
    }
    __syncthreads();

    // histogram over monotone score-bit buckets
    for (int t = tid; t < K; t += NT) atomicAdd(&hist[bucketOf(keysh[t])], 1);
    __syncthreads();

    // inclusive suffix counts via shuffles: hist[b] := #{keys, bucket >= b}.
    // thread t owns buckets {2t, 2t+1}; pair sums -> in-wave suffix scan in
    // registers -> 8 wave totals -> cross-wave add. No LDS dependency chains.
    {
        const int lane = tid & 63;
        const int wv   = tid >> 6;
        const int h0 = hist[2 * tid];
        const int h1 = hist[2 * tid + 1];
        int v = h0 + h1;
        #pragma unroll
        for (int off = 1; off < 64; off <<= 1) {
            const int src = lane + off;
            const int o = __shfl(v, (src < 64) ? src : lane, 64);
            v += (src < 64) ? o : 0;
        }
        // v = inclusive suffix over this wave's pair sums; lane 0 = wave total
        if (lane == 0) wtot[wv] = v;
        __syncthreads();
        int wa = 0;
        #pragma unroll
        for (int w = 0; w < NW; ++w) wa += (w > wv) ? wtot[w] : 0;
        const int T = v + wa;          // inclusive thread-suffix across block
        hist[2 * tid]     = T;         // S[2t]
        hist[2 * tid + 1] = T - h0;    // S[2t+1]
    }
    if (tid == 0) qnSh = 0;
    __syncthreads();

    // qualifiers: candidates whose strictly-above-bucket count < DET
    // (every final rank<DET winner qualifies: rank >= S[b+1])
    for (int t = tid; t < K; t += NT) {
        const int b = bucketOf(keysh[t]);
        const int above = (b + 1 < HB) ? hist[b + 1] : 0;
        if (above < DET) qidx[atomicAdd(&qnSh, 1)] = t;
    }
    __syncthreads();
    const int qn = qnSh;

    // exact rank = above-bucket count + same-bucket greater keys (all of which
    // are themselves qualifiers, since qualification depends only on bucket)
    for (int q = tid; q < qn; q += NT) {
        const unsigned long long kq = keysh[qidx[q]];
        const int bq = bucketOf(kq);
        int rank = (bq + 1 < HB) ? hist[bq + 1] : 0;
        for (int p = 0; p < qn; ++p) {
            const unsigned long long kp2 = keysh[qidx[p]];   // LDS broadcast
            if (kp2 > kq && bucketOf(kp2) == bq) ++rank;
        }
        if (rank < DET) {
            const float sc  = __uint_as_float((unsigned)(kq >> 16));
            const int  slot = 65535 - (int)(kq & 0xFFFFull);
            const float4 bb = gboxes[slot];
            out[rank * 4 + 0] = bb.x;
            out[rank * 4 + 1] = bb.y;
            out[rank * 4 + 2] = bb.z;
            out[rank * 4 + 3] = bb.w;
            out[4 * DET + rank] = sc;                       // score (>0 always)
            out[5 * DET + rank] = (float)(slot / DET + 1);  // label
        }
    }
}

// ---------------------------------------------------------------------------
extern "C" void kernel_launch(void* const* d_in, const int* in_sizes, int n_in,
                              void* d_out, int out_size, void* d_ws, size_t ws_size,
                              hipStream_t stream) {
    (void)in_sizes; (void)n_in; (void)out_size; (void)ws_size;

    const float* class_logits   = (const float*)d_in[0];  // [NP, NC]
    const float* box_regression = (const float*)d_in[1];  // [NP, 4*NC]
    const float* proposals      = (const float*)d_in[2];  // [NP, 4]
    float* out = (float*)d_out;                           // 600 floats

    // Workspace layout (float units; all offsets 16B-aligned)
    float* ws        = (float*)d_ws;
    float* gboxes_f  = ws;                                    // NCAND*4 = 32000
    float* gkeys_f   = gboxes_f + (size_t)NCAND * 4;          // NCAND*2 = 16000
    float* scores_fg = gkeys_f + (size_t)NCAND * 2;           // CF*NP   = 81920
    int*   gcnt      = (int*)(scores_fg + (size_t)CF * NP);   // CF ints

    unsigned long long* gkeys = (unsigned long long*)gkeys_f;
    float4* gboxes = (float4*)gboxes_f;

    void* args[] = {
        (void*)&class_logits, (void*)&box_regression, (void*)&proposals,
        (void*)&gkeys, (void*)&gboxes, (void*)&gcnt,
        (void*)&scores_fg, (void*)&out
    };
    hipLaunchCooperativeKernel((const void*)fused_kernel,
                               dim3(CF), dim3(NT), args, 0, stream);
}

// Round 6
// 88.712 us; speedup vs baseline: 1.3602x; 1.3602x over previous
//
#include <hip/hip_runtime.h>
#include <math.h>

#define NP 1024          // proposals
#define NC 81            // classes incl background
#define CF 80            // foreground classes
#define DET 100          // detections per image
#define SCORE_THRESH 0.05f
#define NMS_THRESH 0.5f
#define BBOX_CLIP 4.135166556742356f   // log(1000/16)
#define IMG_W 1333
#define IMG_H 800

#define NCAND (CF * DET)   // 8000 fixed per-class slots
#define NT 512             // block size (8 waves)
#define NW (NT / 64)       // waves per block

// histogram-select: bucket = clamp((key>>31) - HOFF, 0, HB-1).
// key>>31 == score_bits>>15; score in (0.05, 1] -> raw in [31385, 32512].
// Monotone non-decreasing in key => selection EXACT (same-bucket ties are
// resolved on the full unique 64-bit key).
#define HB   1024
#define HOFF 31385

__device__ __forceinline__ int bucketOf(unsigned long long k) {
    int b = (int)(unsigned)(k >> 31) - HOFF;
    b = b < 0 ? 0 : b;
    b = b > HB - 1 ? HB - 1 : b;
    return b;
}

// Module-static election counter: lives OUTSIDE the poisoned workspace.
// Loaded as 0 at module load; the elected block resets it to 0 at the end of
// every iteration (its fetch_add returned CF-1, so all CF increments of this
// iteration are complete; per-location coherence orders the reset after them).
__device__ int g_done = 0;

// ---------------------------------------------------------------------------
// SINGLE kernel, 80 blocks x 512 threads (normal launch, no grid barrier).
//
// Phase A': per-class self-softmax (redundant x80, but removes the softmax
//   dispatch + one ~10us boundary). Thread t computes proposals 2t, 2t+1
//   scalar-serially with R1's PROVEN bit-exact association:
//   - serial fmaxf over 81 (max is exact under any association)
//   - expf per class, then the butterfly-tree sum: x[l]+=x[64+l] (l<17),
//     then +32,+16,+8,+4, pairs — bit-identical to the wave butterfly
//   - numerator recomputed expf(row[cls+1]-m) (R1-proven identical bits)
//   Scores go to LDS s[1024]; NO cross-block traffic before the election.
// Phase B: R4-verbatim per-class compact/sort/decode/NMS (reads s from LDS).
// Election: one ACQ_REL fetch_add on g_done; 79 blocks exit immediately.
// Phase T: elected block runs R4-verbatim histogram-select topk, zero-fills
//   output rows [K, DET), then resets g_done = 0 for the next iteration.
// ---------------------------------------------------------------------------
__global__ __launch_bounds__(NT) void
fused_kernel(const float* __restrict__ logits,
             const float* __restrict__ rel,
             const float* __restrict__ props,
             unsigned long long* __restrict__ gkeys,
             float4* __restrict__ gboxes,
             int* __restrict__ gcnt,
             float* __restrict__ out) {
    const int cls = blockIdx.x;   // fg class (reference class = cls+1)
    const int tid = threadIdx.x;  // 0..511

    // phase-B arrays union with phase-T keysh (phase-B data dead by then)
    __shared__ __align__(16) unsigned char smem[NCAND * 8];   // 64000 B
    __shared__ __align__(16) float s[NP];                     // class scores
    __shared__ int hist[HB];          // 4 KB (phase T: counts, then suffix S)
    __shared__ int qidx[NCAND];       // 32 KB (phase T qualifier list)
    __shared__ int wtot[NW];          // per-wave totals for suffix scan
    __shared__ int cntSh;
    __shared__ int keptRank[DET];
    __shared__ int keptCnt;
    __shared__ int cshare[CF];
    __shared__ int cbase[CF + 1];
    __shared__ int lastSh;
    __shared__ int qnSh;

    unsigned long long* key = (unsigned long long*)smem;             // 8 KB
    float4* vbox = (float4*)(smem + 8192);                           // 16 KB
    unsigned char* supp = (unsigned char*)(smem + 8192 + 16384);     // 1 KB

    if (tid == 0) cntSh = 0;

    // ---------------- Phase A': self-softmax for this block's class --------
    #pragma unroll 1
    for (int rep = 0; rep < 2; ++rep) {
        const int i = 2 * tid + rep;                 // proposal index
        const float* __restrict__ row = logits + i * NC;

        float x[NC];                                 // static unroll -> regs
        #pragma unroll
        for (int c = 0; c < NC; ++c) x[c] = row[c];

        float m = x[0];
        #pragma unroll
        for (int c = 1; c < NC; ++c) m = fmaxf(m, x[c]);   // max: exact

        #pragma unroll
        for (int c = 0; c < NC; ++c) x[c] = expf(x[c] - m);

        // exact butterfly-tree sum (R1-proven association, absmax 0.0)
        #pragma unroll
        for (int l = 0; l < 17; ++l) x[l] += x[64 + l];
        #pragma unroll
        for (int l = 0; l < 32; ++l) x[l] += x[l + 32];
        #pragma unroll
        for (int l = 0; l < 16; ++l) x[l] += x[l + 16];
        #pragma unroll
        for (int l = 0; l < 8; ++l)  x[l] += x[l + 8];
        #pragma unroll
        for (int l = 0; l < 4; ++l)  x[l] += x[l + 4];
        x[0] += x[2]; x[1] += x[3];
        x[0] += x[1];

        // numerator recomputed (identical bits; avoids dynamic reg index)
        const float num = expf(row[cls + 1] - m);
        s[i] = num / x[0];
    }
    __syncthreads();

    // ---------------- Phase B: per-class NMS (R4 verbatim, s from LDS) -----
    if (tid < NP / 4) {
        const float4 v = ((const float4*)s)[tid];
        const int id0 = tid * 4;
        if (v.x > SCORE_THRESH) { int p = atomicAdd(&cntSh, 1); key[p] = ((unsigned long long)__float_as_uint(v.x) << 16) | (unsigned long long)(1023 - (id0 + 0)); }
        if (v.y > SCORE_THRESH) { int p = atomicAdd(&cntSh, 1); key[p] = ((unsigned long long)__float_as_uint(v.y) << 16) | (unsigned long long)(1023 - (id0 + 1)); }
        if (v.z > SCORE_THRESH) { int p = atomicAdd(&cntSh, 1); key[p] = ((unsigned long long)__float_as_uint(v.z) << 16) | (unsigned long long)(1023 - (id0 + 2)); }
        if (v.w > SCORE_THRESH) { int p = atomicAdd(&cntSh, 1); key[p] = ((unsigned long long)__float_as_uint(v.w) << 16) | (unsigned long long)(1023 - (id0 + 3)); }
    }
    __syncthreads();
    const int cnt = cntSh;

    if (cnt == 0) {
        if (tid == 0) gcnt[cls] = 0;
    } else if (cnt <= 64) {
        // ================== FAST PATH: cnt<=64 (wave 0 active) ==============
        unsigned long long my = 0ull;
        int rk = 0;
        if (tid < cnt) {
            my = key[tid];
            for (int i = 0; i < cnt; ++i) rk += (key[i] > my) ? 1 : 0;
        }
        __syncthreads();
        if (tid < cnt) key[rk] = my;
        __syncthreads();

        if (tid < cnt) {
            const int id = 1023 - (int)(key[tid] & 0xFFFFull);
            const float4 p = ((const float4*)props)[id];
            const float w  = p.z - p.x + 1.0f;
            const float h  = p.w - p.y + 1.0f;
            const float cx = p.x + 0.5f * w;
            const float cy = p.y + 0.5f * h;

            const float4 r = ((const float4*)rel)[id * NC + (cls + 1)];
            const float dx = r.x / 10.0f;
            const float dy = r.y / 10.0f;
            const float dw = fminf(r.z / 5.0f, BBOX_CLIP);
            const float dh = fminf(r.w / 5.0f, BBOX_CLIP);

            const float pcx = dx * w + cx;
            const float pcy = dy * h + cy;
            const float pw  = expf(dw) * w;
            const float ph  = expf(dh) * h;

            float bx1 = pcx - 0.5f * pw;
            float by1 = pcy - 0.5f * ph;
            float bx2 = pcx + 0.5f * pw - 1.0f;
            float by2 = pcy + 0.5f * ph - 1.0f;

            bx1 = fminf(fmaxf(bx1, 0.0f), (float)(IMG_W - 1));
            bx2 = fminf(fmaxf(bx2, 0.0f), (float)(IMG_W - 1));
            by1 = fminf(fmaxf(by1, 0.0f), (float)(IMG_H - 1));
            by2 = fminf(fmaxf(by2, 0.0f), (float)(IMG_H - 1));

            vbox[tid] = make_float4(bx1, by1, bx2, by2);
        }
        __syncthreads();

        unsigned long long mymask = 0ull;
        if (tid < cnt) {
            const float4 bj = vbox[tid];
            const float areaj = (bj.z - bj.x + 1.0f) * (bj.w - bj.y + 1.0f);
            for (int i = 0; i < tid; ++i) {
                const float4 bi = vbox[i];            // LDS broadcast
                const float areai = (bi.z - bi.x + 1.0f) * (bi.w - bi.y + 1.0f);
                const float ltx = fmaxf(bi.x, bj.x);
                const float lty = fmaxf(bi.y, bj.y);
                const float rbx = fminf(bi.z, bj.z);
                const float rby = fminf(bi.w, bj.w);
                const float wq = fmaxf(rbx - ltx + 1.0f, 0.0f);
                const float hq = fmaxf(rby - lty + 1.0f, 0.0f);
                const float inter = wq * hq;
                const float iou = inter / (areai + areaj - inter);
                if (iou > NMS_THRESH) mymask |= (1ull << i);
            }
        }
        // resolve in every wave; only wave-0 results are used (tid<cnt<=64)
        unsigned long long suppbits = 0ull;
        for (int i = 0; i < cnt; ++i) {
            if (!((suppbits >> i) & 1ull)) {
                const unsigned long long vote = __ballot((mymask >> i) & 1ull);
                suppbits |= vote;
            }
        }
        unsigned long long kb = ~suppbits;
        if (cnt < 64) kb &= ((1ull << cnt) - 1ull);
        const int c2 = __popcll(kb);

        if (tid == 0) gcnt[cls] = c2;
        if (tid < cnt && !((suppbits >> tid) & 1ull)) {
            const int kr = __popcll(kb & ((1ull << tid) - 1ull));
            const int slot = cls * DET + kr;
            const unsigned int bits = (unsigned int)(key[tid] >> 16);
            gkeys[slot] = ((unsigned long long)bits << 16) |
                          (unsigned long long)(65535 - slot);
            gboxes[slot] = vbox[tid];
        }
    } else {
        // ===================== SLOW PATH: cnt>64 ============================
        int msz = 1;
        while (msz < cnt) msz <<= 1;
        for (int t = cnt + tid; t < msz; t += NT) key[t] = 0ull;
        __syncthreads();

        for (int k = 2; k <= msz; k <<= 1) {
            for (int jj = k >> 1; jj > 0; jj >>= 1) {
                for (int t = tid; t < msz; t += NT) {
                    const int ixj = t ^ jj;
                    if (ixj > t) {
                        const unsigned long long a = key[t], b = key[ixj];
                        const bool tAfter = (a < b);
                        const bool dirAsc = ((t & k) == 0);
                        if (dirAsc ? tAfter : !tAfter) { key[t] = b; key[ixj] = a; }
                    }
                }
                __syncthreads();
            }
        }

        for (int t = tid; t < cnt; t += NT) {
            const int id = 1023 - (int)(key[t] & 0xFFFFull);
            const float4 p = ((const float4*)props)[id];
            const float w  = p.z - p.x + 1.0f;
            const float h  = p.w - p.y + 1.0f;
            const float cx = p.x + 0.5f * w;
            const float cy = p.y + 0.5f * h;

            const float4 r = ((const float4*)rel)[id * NC + (cls + 1)];
            const float dx = r.x / 10.0f;
            const float dy = r.y / 10.0f;
            const float dw = fminf(r.z / 5.0f, BBOX_CLIP);
            const float dh = fminf(r.w / 5.0f, BBOX_CLIP);

            const float pcx = dx * w + cx;
            const float pcy = dy * h + cy;
            const float pw  = expf(dw) * w;
            const float ph  = expf(dh) * h;

            float bx1 = pcx - 0.5f * pw;
            float by1 = pcy - 0.5f * ph;
            float bx2 = pcx + 0.5f * pw - 1.0f;
            float by2 = pcy + 0.5f * ph - 1.0f;

            bx1 = fminf(fmaxf(bx1, 0.0f), (float)(IMG_W - 1));
            bx2 = fminf(fmaxf(bx2, 0.0f), (float)(IMG_W - 1));
            by1 = fminf(fmaxf(by1, 0.0f), (float)(IMG_H - 1));
            by2 = fminf(fmaxf(by2, 0.0f), (float)(IMG_H - 1));

            vbox[t] = make_float4(bx1, by1, bx2, by2);
            supp[t] = 0;
        }
        __syncthreads();

        for (int i = 0; i < cnt; ++i) {
            if (!supp[i]) {
                const float4 bi = vbox[i];
                const float areai = (bi.z - bi.x + 1.0f) * (bi.w - bi.y + 1.0f);
                for (int t = i + 1 + tid; t < cnt; t += NT) {
                    const float4 bj = vbox[t];
                    const float areaj = (bj.z - bj.x + 1.0f) * (bj.w - bj.y + 1.0f);
                    const float ltx = fmaxf(bi.x, bj.x);
                    const float lty = fmaxf(bi.y, bj.y);
                    const float rbx = fminf(bi.z, bj.z);
                    const float rby = fminf(bi.w, bj.w);
                    const float wq = fmaxf(rbx - ltx + 1.0f, 0.0f);
                    const float hq = fmaxf(rby - lty + 1.0f, 0.0f);
                    const float inter = wq * hq;
                    const float iou = inter / (areai + areaj - inter);
                    if (iou > NMS_THRESH) supp[t] = 1;
                }
            }
            __syncthreads();
        }

        if (tid == 0) {
            int c2 = 0;
            for (int r = 0; r < cnt && c2 < DET; ++r)
                if (!supp[r]) keptRank[c2++] = r;
            keptCnt = c2;
            gcnt[cls] = c2;
        }
        __syncthreads();

        const int kc = keptCnt;
        for (int t = tid; t < kc; t += NT) {
            const int r = keptRank[t];
            const int slot = cls * DET + t;
            const unsigned int bits = (unsigned int)(key[r] >> 16);
            gkeys[slot] = ((unsigned long long)bits << 16) |
                          (unsigned long long)(65535 - slot);
            gboxes[slot] = vbox[r];
        }
    }

    // ---------------- last-block election (NO spinning) ---------------------
    __syncthreads();   // all this block's writes drained before the release
    if (tid == 0) {
        const int prev = __hip_atomic_fetch_add(&g_done, 1, __ATOMIC_ACQ_REL,
                                                __HIP_MEMORY_SCOPE_AGENT);
        lastSh = (prev == CF - 1);
    }
    __syncthreads();
    if (!lastSh) return;   // 79 blocks retire immediately

    // ---------------- Phase T: elected-block histogram-select topk ----------
    if (tid < CF) cshare[tid] = gcnt[tid];
    __syncthreads();
    if (tid <= CF) {
        int acc = 0;
        for (int i = 0; i < tid; ++i) acc += cshare[i];   // independent loads
        cbase[tid] = acc;
    }
    for (int t = tid; t < HB; t += NT) hist[t] = 0;
    __syncthreads();
    const int K = cbase[CF];

    // zero-fill output rows [K, DET) — ranks are dense, so rows < min(K,DET)
    // are each written exactly once by their winner below.
    for (int r = K + tid; r < DET; r += NT) {
        out[r * 4 + 0] = 0.0f; out[r * 4 + 1] = 0.0f;
        out[r * 4 + 2] = 0.0f; out[r * 4 + 3] = 0.0f;
        out[4 * DET + r] = 0.0f;
        out[5 * DET + r] = 0.0f;
    }

    // flat parallel gather of the compacted key array (coalesced, ~16 iters)
    unsigned long long* keysh = (unsigned long long*)smem;   // reuses phase-B
    for (int g = tid; g < NCAND; g += NT) {
        const int c = g / DET;          // const-div -> magic mul
        const int j = g - c * DET;
        if (j < cshare[c]) keysh[cbase[c] + j] = gkeys[g];
    }
    __syncthreads();

    // histogram over monotone score-bit buckets
    for (int t = tid; t < K; t += NT) atomicAdd(&hist[bucketOf(keysh[t])], 1);
    __syncthreads();

    // inclusive suffix counts via shuffles: hist[b] := #{keys, bucket >= b}.
    // thread t owns buckets {2t, 2t+1}; pair sums -> in-wave suffix scan in
    // registers -> 8 wave totals -> cross-wave add. No LDS dependency chains.
    {
        const int lane = tid & 63;
        const int wv   = tid >> 6;
        const int h0 = hist[2 * tid];
        const int h1 = hist[2 * tid + 1];
        int v = h0 + h1;
        #pragma unroll
        for (int off = 1; off < 64; off <<= 1) {
            const int src = lane + off;
            const int o = __shfl(v, (src < 64) ? src : lane, 64);
            v += (src < 64) ? o : 0;
        }
        // v = inclusive suffix over this wave's pair sums; lane 0 = wave total
        if (lane == 0) wtot[wv] = v;
        __syncthreads();
        int wa = 0;
        #pragma unroll
        for (int w = 0; w < NW; ++w) wa += (w > wv) ? wtot[w] : 0;
        const int T = v + wa;          // inclusive thread-suffix across block
        hist[2 * tid]     = T;         // S[2t]
        hist[2 * tid + 1] = T - h0;    // S[2t+1]
    }
    if (tid == 0) qnSh = 0;
    __syncthreads();

    // qualifiers: candidates whose strictly-above-bucket count < DET
    // (every final rank<DET winner qualifies: rank >= S[b+1])
    for (int t = tid; t < K; t += NT) {
        const int b = bucketOf(keysh[t]);
        const int above = (b + 1 < HB) ? hist[b + 1] : 0;
        if (above < DET) qidx[atomicAdd(&qnSh, 1)] = t;
    }
    __syncthreads();
    const int qn = qnSh;

    // exact rank = above-bucket count + same-bucket greater keys (all of which
    // are themselves qualifiers, since qualification depends only on bucket)
    for (int q = tid; q < qn; q += NT) {
        const unsigned long long kq = keysh[qidx[q]];
        const int bq = bucketOf(kq);
        int rank = (bq + 1 < HB) ? hist[bq + 1] : 0;
        for (int p = 0; p < qn; ++p) {
            const unsigned long long kp2 = keysh[qidx[p]];   // LDS broadcast
            if (kp2 > kq && bucketOf(kp2) == bq) ++rank;
        }
        if (rank < DET) {
            const float sc  = __uint_as_float((unsigned)(kq >> 16));
            const int  slot = 65535 - (int)(kq & 0xFFFFull);
            const float4 bb = gboxes[slot];
            out[rank * 4 + 0] = bb.x;
            out[rank * 4 + 1] = bb.y;
            out[rank * 4 + 2] = bb.z;
            out[rank * 4 + 3] = bb.w;
            out[4 * DET + rank] = sc;                       // score (>0 always)
            out[5 * DET + rank] = (float)(slot / DET + 1);  // label
        }
    }

    // self-clean the election counter for the next iteration (all CF
    // increments of this iteration are complete: our RMW returned CF-1).
    if (tid == 0)
        __hip_atomic_store(&g_done, 0, __ATOMIC_RELAXED,
                           __HIP_MEMORY_SCOPE_AGENT);
}

// ---------------------------------------------------------------------------
extern "C" void kernel_launch(void* const* d_in, const int* in_sizes, int n_in,
                              void* d_out, int out_size, void* d_ws, size_t ws_size,
                              hipStream_t stream) {
    (void)in_sizes; (void)n_in; (void)out_size; (void)ws_size;

    const float* class_logits   = (const float*)d_in[0];  // [NP, NC]
    const float* box_regression = (const float*)d_in[1];  // [NP, 4*NC]
    const float* proposals      = (const float*)d_in[2];  // [NP, 4]
    float* out = (float*)d_out;                           // 600 floats

    // Workspace layout (float units; all offsets 16B-aligned)
    float* ws        = (float*)d_ws;
    float* gboxes_f  = ws;                                    // NCAND*4 = 32000
    float* gkeys_f   = gboxes_f + (size_t)NCAND * 4;          // NCAND*2 = 16000
    int*   gcnt      = (int*)(gkeys_f + (size_t)NCAND * 2);   // CF ints

    unsigned long long* gkeys = (unsigned long long*)gkeys_f;
    float4* gboxes = (float4*)gboxes_f;

    fused_kernel<<<dim3(CF), dim3(NT), 0, stream>>>(
        class_logits, box_regression, proposals, gkeys, gboxes, gcnt, out);
}

// Round 7
// 80.218 us; speedup vs baseline: 1.5042x; 1.1059x over previous
//
#include <hip/hip_runtime.h>
#include <math.h>

#define NP 1024          // proposals
#define NC 81            // classes incl background
#define CF 80            // foreground classes
#define DET 100          // detections per image
#define SCORE_THRESH 0.05f
#define NMS_THRESH 0.5f
#define BBOX_CLIP 4.135166556742356f   // log(1000/16)
#define IMG_W 1333
#define IMG_H 800

#define NCAND (CF * DET)   // 8000 fixed per-class slots
#define NT 512             // nms_topk block size (8 waves)
#define NW (NT / 64)       // waves per block

// histogram-select: bucket = clamp((key>>31) - HOFF, 0, HB-1).
// key>>31 == score_bits>>15; score in (0.05, 1] -> raw in [31385, 32512].
// Monotone non-decreasing in key => selection EXACT (same-bucket ties are
// resolved on the full unique 64-bit key).
#define HB   1024
#define HOFF 31385

__device__ __forceinline__ int bucketOf(unsigned long long k) {
    int b = (int)(unsigned)(k >> 31) - HOFF;
    b = b < 0 ? 0 : b;
    b = b > HB - 1 ? HB - 1 : b;
    return b;
}

// Module-static election counter (R6-proven): lives OUTSIDE the poisoned
// workspace; loaded as 0 at module load; elected block resets it to 0 each
// iteration (its fetch_add returned CF-1 => all CF increments complete).
__device__ int g_done = 0;

// ---------------------------------------------------------------------------
// Kernel 1: per-proposal row stats (m, S) — R0's bit-exact-proven butterfly
// wave softmax, but writing only the 8-byte (max, sum) per row instead of
// 80 scores (320 KB -> 8 KB of stores). One wave per proposal, 4/block.
// ---------------------------------------------------------------------------
__global__ __launch_bounds__(256) void
rowstat_kernel(const float* __restrict__ logits,
               float2* __restrict__ mS) {
    const int wave = threadIdx.x >> 6;
    const int lane = threadIdx.x & 63;
    const int i = blockIdx.x * 4 + wave;          // proposal index

    const float x0 = logits[i * NC + lane];
    const float x1 = (lane < NC - 64) ? logits[i * NC + 64 + lane] : -INFINITY;

    float m = fmaxf(x0, x1);
    for (int off = 32; off > 0; off >>= 1) m = fmaxf(m, __shfl_xor(m, off));

    const float e0 = expf(x0 - m);
    const float e1 = (lane < NC - 64) ? expf(x1 - m) : 0.0f;
    float sum = e0 + e1;
    for (int off = 32; off > 0; off >>= 1) sum += __shfl_xor(sum, off);

    if (lane == 0) mS[i] = make_float2(m, sum);
}

// ---------------------------------------------------------------------------
// Kernel 2: per-class NMS (R4-verbatim fast/slow paths) + LAST-BLOCK topk.
// 80 blocks x 512 threads. Phase B reconstructs this class's scores as
// expf(logit[i][cls+1] - m_i) / S_i  — same input bits, same m/S, same ops
// as R0's e0/sum => bit-identical scores => identical keys (absmax 0.0).
// Election: one ACQ_REL fetch_add on g_done; 79 blocks exit immediately;
// elected block runs histogram-select topk + zero-fills rows [K, DET).
// ---------------------------------------------------------------------------
__global__ __launch_bounds__(NT) void
nms_topk_kernel(const float* __restrict__ logits,
                const float2* __restrict__ mS,
                const float* __restrict__ rel,
                const float* __restrict__ props,
                unsigned long long* __restrict__ gkeys,
                float4* __restrict__ gboxes,
                int* __restrict__ gcnt,
                float* __restrict__ out) {
    const int cls = blockIdx.x;   // fg class (reference class = cls+1)
    const int tid = threadIdx.x;  // 0..511

    // phase-B arrays union with phase-T keysh (phase-B data dead by then)
    __shared__ __align__(16) unsigned char smem[NCAND * 8];   // 64000 B
    __shared__ int hist[HB];          // 4 KB (phase T: counts, then suffix S)
    __shared__ int qidx[NCAND];       // 32 KB (phase T qualifier list)
    __shared__ int wtot[NW];          // per-wave totals for suffix scan
    __shared__ int cntSh;
    __shared__ int keptRank[DET];
    __shared__ int keptCnt;
    __shared__ int cshare[CF];
    __shared__ int cbase[CF + 1];
    __shared__ int lastSh;
    __shared__ int qnSh;

    unsigned long long* key = (unsigned long long*)smem;             // 8 KB
    float4* vbox = (float4*)(smem + 8192);                           // 16 KB
    unsigned char* supp = (unsigned char*)(smem + 8192 + 16384);     // 1 KB

    if (tid == 0) cntSh = 0;
    __syncthreads();

    // ---- threshold compaction with inline score reconstruction ------------
    // thread t (<256) handles proposals 4t..4t+3: coalesced (m,S) loads +
    // 4 scattered L2-hot logit-column dwords + 4 expf. Bit-identical scores.
    if (tid < NP / 4) {
        const int id0 = tid * 4;
        const float4 a = ((const float4*)mS)[tid * 2];       // mS[id0..id0+1]
        const float4 b = ((const float4*)mS)[tid * 2 + 1];   // mS[id0+2..+3]
        const float x0 = logits[(id0 + 0) * NC + (cls + 1)];
        const float x1 = logits[(id0 + 1) * NC + (cls + 1)];
        const float x2 = logits[(id0 + 2) * NC + (cls + 1)];
        const float x3 = logits[(id0 + 3) * NC + (cls + 1)];
        const float s0 = expf(x0 - a.x) / a.y;
        const float s1 = expf(x1 - a.z) / a.w;
        const float s2 = expf(x2 - b.x) / b.y;
        const float s3 = expf(x3 - b.z) / b.w;
        if (s0 > SCORE_THRESH) { int p = atomicAdd(&cntSh, 1); key[p] = ((unsigned long long)__float_as_uint(s0) << 16) | (unsigned long long)(1023 - (id0 + 0)); }
        if (s1 > SCORE_THRESH) { int p = atomicAdd(&cntSh, 1); key[p] = ((unsigned long long)__float_as_uint(s1) << 16) | (unsigned long long)(1023 - (id0 + 1)); }
        if (s2 > SCORE_THRESH) { int p = atomicAdd(&cntSh, 1); key[p] = ((unsigned long long)__float_as_uint(s2) << 16) | (unsigned long long)(1023 - (id0 + 2)); }
        if (s3 > SCORE_THRESH) { int p = atomicAdd(&cntSh, 1); key[p] = ((unsigned long long)__float_as_uint(s3) << 16) | (unsigned long long)(1023 - (id0 + 3)); }
    }
    __syncthreads();
    const int cnt = cntSh;

    if (cnt == 0) {
        if (tid == 0) gcnt[cls] = 0;
    } else if (cnt <= 64) {
        // ================== FAST PATH: cnt<=64 (wave 0 active) ==============
        unsigned long long my = 0ull;
        int rk = 0;
        if (tid < cnt) {
            my = key[tid];
            for (int i = 0; i < cnt; ++i) rk += (key[i] > my) ? 1 : 0;
        }
        __syncthreads();
        if (tid < cnt) key[rk] = my;
        __syncthreads();

        if (tid < cnt) {
            const int id = 1023 - (int)(key[tid] & 0xFFFFull);
            const float4 p = ((const float4*)props)[id];
            const float w  = p.z - p.x + 1.0f;
            const float h  = p.w - p.y + 1.0f;
            const float cx = p.x + 0.5f * w;
            const float cy = p.y + 0.5f * h;

            const float4 r = ((const float4*)rel)[id * NC + (cls + 1)];
            const float dx = r.x / 10.0f;
            const float dy = r.y / 10.0f;
            const float dw = fminf(r.z / 5.0f, BBOX_CLIP);
            const float dh = fminf(r.w / 5.0f, BBOX_CLIP);

            const float pcx = dx * w + cx;
            const float pcy = dy * h + cy;
            const float pw  = expf(dw) * w;
            const float ph  = expf(dh) * h;

            float bx1 = pcx - 0.5f * pw;
            float by1 = pcy - 0.5f * ph;
            float bx2 = pcx + 0.5f * pw - 1.0f;
            float by2 = pcy + 0.5f * ph - 1.0f;

            bx1 = fminf(fmaxf(bx1, 0.0f), (float)(IMG_W - 1));
            bx2 = fminf(fmaxf(bx2, 0.0f), (float)(IMG_W - 1));
            by1 = fminf(fmaxf(by1, 0.0f), (float)(IMG_H - 1));
            by2 = fminf(fmaxf(by2, 0.0f), (float)(IMG_H - 1));

            vbox[tid] = make_float4(bx1, by1, bx2, by2);
        }
        __syncthreads();

        unsigned long long mymask = 0ull;
        if (tid < cnt) {
            const float4 bj = vbox[tid];
            const float areaj = (bj.z - bj.x + 1.0f) * (bj.w - bj.y + 1.0f);
            for (int i = 0; i < tid; ++i) {
                const float4 bi = vbox[i];            // LDS broadcast
                const float areai = (bi.z - bi.x + 1.0f) * (bi.w - bi.y + 1.0f);
                const float ltx = fmaxf(bi.x, bj.x);
                const float lty = fmaxf(bi.y, bj.y);
                const float rbx = fminf(bi.z, bj.z);
                const float rby = fminf(bi.w, bj.w);
                const float wq = fmaxf(rbx - ltx + 1.0f, 0.0f);
                const float hq = fmaxf(rby - lty + 1.0f, 0.0f);
                const float inter = wq * hq;
                const float iou = inter / (areai + areaj - inter);
                if (iou > NMS_THRESH) mymask |= (1ull << i);
            }
        }
        // resolve in every wave; only wave-0 results are used (tid<cnt<=64)
        unsigned long long suppbits = 0ull;
        for (int i = 0; i < cnt; ++i) {
            if (!((suppbits >> i) & 1ull)) {
                const unsigned long long vote = __ballot((mymask >> i) & 1ull);
                suppbits |= vote;
            }
        }
        unsigned long long kb = ~suppbits;
        if (cnt < 64) kb &= ((1ull << cnt) - 1ull);
        const int c2 = __popcll(kb);

        if (tid == 0) gcnt[cls] = c2;
        if (tid < cnt && !((suppbits >> tid) & 1ull)) {
            const int kr = __popcll(kb & ((1ull << tid) - 1ull));
            const int slot = cls * DET + kr;
            const unsigned int bits = (unsigned int)(key[tid] >> 16);
            gkeys[slot] = ((unsigned long long)bits << 16) |
                          (unsigned long long)(65535 - slot);
            gboxes[slot] = vbox[tid];
        }
    } else {
        // ===================== SLOW PATH: cnt>64 ============================
        int msz = 1;
        while (msz < cnt) msz <<= 1;
        for (int t = cnt + tid; t < msz; t += NT) key[t] = 0ull;
        __syncthreads();

        for (int k = 2; k <= msz; k <<= 1) {
            for (int jj = k >> 1; jj > 0; jj >>= 1) {
                for (int t = tid; t < msz; t += NT) {
                    const int ixj = t ^ jj;
                    if (ixj > t) {
                        const unsigned long long a = key[t], b = key[ixj];
                        const bool tAfter = (a < b);
                        const bool dirAsc = ((t & k) == 0);
                        if (dirAsc ? tAfter : !tAfter) { key[t] = b; key[ixj] = a; }
                    }
                }
                __syncthreads();
            }
        }

        for (int t = tid; t < cnt; t += NT) {
            const int id = 1023 - (int)(key[t] & 0xFFFFull);
            const float4 p = ((const float4*)props)[id];
            const float w  = p.z - p.x + 1.0f;
            const float h  = p.w - p.y + 1.0f;
            const float cx = p.x + 0.5f * w;
            const float cy = p.y + 0.5f * h;

            const float4 r = ((const float4*)rel)[id * NC + (cls + 1)];
            const float dx = r.x / 10.0f;
            const float dy = r.y / 10.0f;
            const float dw = fminf(r.z / 5.0f, BBOX_CLIP);
            const float dh = fminf(r.w / 5.0f, BBOX_CLIP);

            const float pcx = dx * w + cx;
            const float pcy = dy * h + cy;
            const float pw  = expf(dw) * w;
            const float ph  = expf(dh) * h;

            float bx1 = pcx - 0.5f * pw;
            float by1 = pcy - 0.5f * ph;
            float bx2 = pcx + 0.5f * pw - 1.0f;
            float by2 = pcy + 0.5f * ph - 1.0f;

            bx1 = fminf(fmaxf(bx1, 0.0f), (float)(IMG_W - 1));
            bx2 = fminf(fmaxf(bx2, 0.0f), (float)(IMG_W - 1));
            by1 = fminf(fmaxf(by1, 0.0f), (float)(IMG_H - 1));
            by2 = fminf(fmaxf(by2, 0.0f), (float)(IMG_H - 1));

            vbox[t] = make_float4(bx1, by1, bx2, by2);
            supp[t] = 0;
        }
        __syncthreads();

        for (int i = 0; i < cnt; ++i) {
            if (!supp[i]) {
                const float4 bi = vbox[i];
                const float areai = (bi.z - bi.x + 1.0f) * (bi.w - bi.y + 1.0f);
                for (int t = i + 1 + tid; t < cnt; t += NT) {
                    const float4 bj = vbox[t];
                    const float areaj = (bj.z - bj.x + 1.0f) * (bj.w - bj.y + 1.0f);
                    const float ltx = fmaxf(bi.x, bj.x);
                    const float lty = fmaxf(bi.y, bj.y);
                    const float rbx = fminf(bi.z, bj.z);
                    const float rby = fminf(bi.w, bj.w);
                    const float wq = fmaxf(rbx - ltx + 1.0f, 0.0f);
                    const float hq = fmaxf(rby - lty + 1.0f, 0.0f);
                    const float inter = wq * hq;
                    const float iou = inter / (areai + areaj - inter);
                    if (iou > NMS_THRESH) supp[t] = 1;
                }
            }
            __syncthreads();
        }

        if (tid == 0) {
            int c2 = 0;
            for (int r = 0; r < cnt && c2 < DET; ++r)
                if (!supp[r]) keptRank[c2++] = r;
            keptCnt = c2;
            gcnt[cls] = c2;
        }
        __syncthreads();

        const int kc = keptCnt;
        for (int t = tid; t < kc; t += NT) {
            const int r = keptRank[t];
            const int slot = cls * DET + t;
            const unsigned int bits = (unsigned int)(key[r] >> 16);
            gkeys[slot] = ((unsigned long long)bits << 16) |
                          (unsigned long long)(65535 - slot);
            gboxes[slot] = vbox[r];
        }
    }

    // ---------------- last-block election (NO spinning) ---------------------
    __syncthreads();   // all this block's writes drained before the release
    if (tid == 0) {
        const int prev = __hip_atomic_fetch_add(&g_done, 1, __ATOMIC_ACQ_REL,
                                                __HIP_MEMORY_SCOPE_AGENT);
        lastSh = (prev == CF - 1);
    }
    __syncthreads();
    if (!lastSh) return;   // 79 blocks retire immediately

    // ---------------- Phase T: elected-block histogram-select topk ----------
    if (tid < CF) cshare[tid] = gcnt[tid];
    __syncthreads();
    if (tid <= CF) {
        int acc = 0;
        for (int i = 0; i < tid; ++i) acc += cshare[i];   // independent loads
        cbase[tid] = acc;
    }
    for (int t = tid; t < HB; t += NT) hist[t] = 0;
    __syncthreads();
    const int K = cbase[CF];

    // zero-fill output rows [K, DET) — ranks are dense, so rows < min(K,DET)
    // are each written exactly once by their winner below. (R6-proven.)
    for (int r = K + tid; r < DET; r += NT) {
        out[r * 4 + 0] = 0.0f; out[r * 4 + 1] = 0.0f;
        out[r * 4 + 2] = 0.0f; out[r * 4 + 3] = 0.0f;
        out[4 * DET + r] = 0.0f;
        out[5 * DET + r] = 0.0f;
    }

    // flat parallel gather of the compacted key array (coalesced, ~16 iters)
    unsigned long long* keysh = (unsigned long long*)smem;   // reuses phase-B
    for (int g = tid; g < NCAND; g += NT) {
        const int c = g / DET;          // const-div -> magic mul
        const int j = g - c * DET;
        if (j < cshare[c]) keysh[cbase[c] + j] = gkeys[g];
    }
    __syncthreads();

    // histogram over monotone score-bit buckets
    for (int t = tid; t < K; t += NT) atomicAdd(&hist[bucketOf(keysh[t])], 1);
    __syncthreads();

    // inclusive suffix counts via shuffles: hist[b] := #{keys, bucket >= b}.
    // thread t owns buckets {2t, 2t+1}; pair sums -> in-wave suffix scan in
    // registers -> 8 wave totals -> cross-wave add. No LDS dependency chains.
    {
        const int lane = tid & 63;
        const int wv   = tid >> 6;
        const int h0 = hist[2 * tid];
        const int h1 = hist[2 * tid + 1];
        int v = h0 + h1;
        #pragma unroll
        for (int off = 1; off < 64; off <<= 1) {
            const int src = lane + off;
            const int o = __shfl(v, (src < 64) ? src : lane, 64);
            v += (src < 64) ? o : 0;
        }
        // v = inclusive suffix over this wave's pair sums; lane 0 = wave total
        if (lane == 0) wtot[wv] = v;
        __syncthreads();
        int wa = 0;
        #pragma unroll
        for (int w = 0; w < NW; ++w) wa += (w > wv) ? wtot[w] : 0;
        const int T = v + wa;          // inclusive thread-suffix across block
        hist[2 * tid]     = T;         // S[2t]
        hist[2 * tid + 1] = T - h0;    // S[2t+1]
    }
    if (tid == 0) qnSh = 0;
    __syncthreads();

    // qualifiers: candidates whose strictly-above-bucket count < DET
    // (every final rank<DET winner qualifies: rank >= S[b+1])
    for (int t = tid; t < K; t += NT) {
        const int b = bucketOf(keysh[t]);
        const int above = (b + 1 < HB) ? hist[b + 1] : 0;
        if (above < DET) qidx[atomicAdd(&qnSh, 1)] = t;
    }
    __syncthreads();
    const int qn = qnSh;

    // exact rank = above-bucket count + same-bucket greater keys (all of which
    // are themselves qualifiers, since qualification depends only on bucket)
    for (int q = tid; q < qn; q += NT) {
        const unsigned long long kq = keysh[qidx[q]];
        const int bq = bucketOf(kq);
        int rank = (bq + 1 < HB) ? hist[bq + 1] : 0;
        for (int p = 0; p < qn; ++p) {
            const unsigned long long kp2 = keysh[qidx[p]];   // LDS broadcast
            if (kp2 > kq && bucketOf(kp2) == bq) ++rank;
        }
        if (rank < DET) {
            const float sc  = __uint_as_float((unsigned)(kq >> 16));
            const int  slot = 65535 - (int)(kq & 0xFFFFull);
            const float4 bb = gboxes[slot];
            out[rank * 4 + 0] = bb.x;
            out[rank * 4 + 1] = bb.y;
            out[rank * 4 + 2] = bb.z;
            out[rank * 4 + 3] = bb.w;
            out[4 * DET + rank] = sc;                       // score (>0 always)
            out[5 * DET + rank] = (float)(slot / DET + 1);  // label
        }
    }

    // self-clean the election counter for the next iteration (all CF
    // increments of this iteration are complete: our RMW returned CF-1).
    if (tid == 0)
        __hip_atomic_store(&g_done, 0, __ATOMIC_RELAXED,
                           __HIP_MEMORY_SCOPE_AGENT);
}

// ---------------------------------------------------------------------------
extern "C" void kernel_launch(void* const* d_in, const int* in_sizes, int n_in,
                              void* d_out, int out_size, void* d_ws, size_t ws_size,
                              hipStream_t stream) {
    (void)in_sizes; (void)n_in; (void)out_size; (void)ws_size;

    const float* class_logits   = (const float*)d_in[0];  // [NP, NC]
    const float* box_regression = (const float*)d_in[1];  // [NP, 4*NC]
    const float* proposals      = (const float*)d_in[2];  // [NP, 4]
    float* out = (float*)d_out;                           // 600 floats

    // Workspace layout (float units; all offsets 16B-aligned)
    float* ws        = (float*)d_ws;
    float* gboxes_f  = ws;                                    // NCAND*4 = 32000
    float* gkeys_f   = gboxes_f + (size_t)NCAND * 4;          // NCAND*2 = 16000
    float* mS_f      = gkeys_f + (size_t)NCAND * 2;           // NP*2    = 2048
    int*   gcnt      = (int*)(mS_f + (size_t)NP * 2);         // CF ints

    unsigned long long* gkeys = (unsigned long long*)gkeys_f;
    float4* gboxes = (float4*)gboxes_f;
    float2* mS = (float2*)mS_f;

    rowstat_kernel<<<dim3(NP / 4), dim3(256), 0, stream>>>(class_logits, mS);

    nms_topk_kernel<<<dim3(CF), dim3(NT), 0, stream>>>(
        class_logits, mS, box_regression, proposals,
        gkeys, gboxes, gcnt, out);
}